// Round 1
// baseline (234.184 us; speedup 1.0000x reference)
//
#include <hip/hip_runtime.h>
#include <math.h>
#include <stdint.h>

// B=8, S=2048, D=512 single-head self-attention, fp32 in/out, fp16 MFMA inside.
// Round 8 = round-7 structure (220.8us) + pipelined GEMM core:
//   - double-buffered LDS (As0/Bs0/As1/Bs1, 64KB), raw s_barrier (NOT
//     __syncthreads -> no vmcnt(0) drain), counted s_waitcnt vmcnt(8):
//     next K-tile's 8 global_load_lds stay in flight across the barrier
//     while the current tile's 32 MFMAs run. This attacks the measured
//     av_mfma profile (MfmaUtil 25%, HBM 17%, occ 17.5% = latency-bound:
//     old core exposed full load latency every K-step via back-to-back
//     __syncthreads with zero issue->use distance).
//   - av aliases its l_s rowsum buffer onto the dead staging LDS to stay
//     at exactly 64KB static shared (2 blocks/CU).
// Round-7: XCD-aware block mapping (batch=bid&7 pins a batch's working set
// to one XCD L2; proj y-blocks stride 128=0 mod 8 -> same XCD).
// Round-6 lesson (fused flash attempt, 324us): 16 vmcnt(0) barrier pairs per
// j-tile is barrier-death; keep the unfused two-GEMM form.
//
//  1. prep:        Xh = fp16(x);  W*T = fp16(W^T) for q,k,v
//  2. proj_mfma:   z=0: Qh = (Xh.Wq + bq)/sqrt(512)   z=1: Kh = Xh.Wk + bk
//                  z=2: Vt[b][d][s] = (Xh.Wv + bv)^T  (direct transposed GEMM)
//  3. scores_mfma: P[b] = fp16(exp(Qh.Kh^T))  UNNORMALIZED (scores ~N(0,1),
//                  exp<=~300 in fp16 range; verified r3-r5, absmax 2e-3)
//  4. av_mfma:     out[b] = (P.V) * mask[row] / l[row]; l = rowsum(P) computed
//                  inside the K-loop by dotting A-frags with ones (r5 win).
//
// GEMM core: 128x128 tile, 4 waves (2x2), 4x4 16x16x32 f16 MFMA, BK=64,
// XOR-swizzled 16B chunks (0 bank conflicts, verified r3),
// global_load_lds width=16, 32 MFMAs per barrier pair, 2-deep prefetch.

typedef _Float16 f16x8 __attribute__((ext_vector_type(8)));
typedef _Float16 f16x4 __attribute__((ext_vector_type(4)));
typedef _Float16 f16x2 __attribute__((ext_vector_type(2)));
typedef float f32x4 __attribute__((ext_vector_type(4)));

__device__ __forceinline__ void async16(const _Float16* g, _Float16* l) {
    __builtin_amdgcn_global_load_lds(
        (const __attribute__((address_space(1))) unsigned int*)(uintptr_t)g,
        (__attribute__((address_space(3))) unsigned int*)(unsigned int)(uintptr_t)l,
        16, 0, 0);
}

__device__ __forceinline__ float frag_sum8(f16x8 v, float acc) {
#if __has_builtin(__builtin_amdgcn_fdot2)
    const f16x2 one2 = {(_Float16)1.f, (_Float16)1.f};
    const f16x2* p = (const f16x2*)&v;
    acc = __builtin_amdgcn_fdot2(p[0], one2, acc, false);
    acc = __builtin_amdgcn_fdot2(p[1], one2, acc, false);
    acc = __builtin_amdgcn_fdot2(p[2], one2, acc, false);
    acc = __builtin_amdgcn_fdot2(p[3], one2, acc, false);
#else
#pragma unroll
    for (int j = 0; j < 8; j++) acc += (float)v[j];
#endif
    return acc;
}

// acc[4][4] += A[row0:+128][0:K] . B[col0:+128][0:K]^T ; A:[M][K] B:[N][K]
// sm: 4 * 128*64 halves = 64KB: [buf0: As|Bs][buf1: As|Bs]
template <bool WITH_RS>
__device__ __forceinline__ void mfma_gemm_core64(
    const _Float16* __restrict__ A, int lda,
    const _Float16* __restrict__ B, int ldb,
    int K, int row0, int col0,
    _Float16* sm, f32x4 acc[4][4], float rs[4])
{
    const int tid  = threadIdx.x;
    const int lane = tid & 63;
    const int wave = tid >> 6;
    const int wm   = wave >> 1, wn = wave & 1;

    const int rc  = lane >> 3;                 // row within 8-row chunk
    const int swz = ((lane & 7) ^ rc) * 8;     // swizzled k-offset (halves)

    const _Float16* gA[4]; const _Float16* gB[4];
    int lA[4], lB[4];                          // half-offsets within one buffer
#pragma unroll
    for (int i = 0; i < 4; i++) {
        int c = wave * 4 + i;
        gA[i] = A + (size_t)(row0 + 8 * c + rc) * lda + swz;
        gB[i] = B + (size_t)(col0 + 8 * c + rc) * ldb + swz;
        lA[i] = c * 512;
        lB[i] = 8192 + c * 512;
    }

    const int fr = lane & 15;
    const int q  = lane >> 4;
    const int fx = fr & 7;

    // prologue: stage k0=0 into buf0 (waves write disjoint chunks, no sync)
#pragma unroll
    for (int i = 0; i < 4; i++) {
        async16(gA[i], sm + lA[i]);
        async16(gB[i], sm + lB[i]);
    }

    int cur = 0;
    for (int k0 = 0;; k0 += 64) {
        const bool more = (k0 + 64) < K;
        if (more) {
            const int nb = (cur ^ 1) * 16384;
#pragma unroll
            for (int i = 0; i < 4; i++) {
                async16(gA[i] + k0 + 64, sm + nb + lA[i]);
                async16(gB[i] + k0 + 64, sm + nb + lB[i]);
            }
            // wait only for buf[cur]'s 8 loads; next tile's 8 stay in flight
            asm volatile("s_waitcnt vmcnt(8)" ::: "memory");
        } else {
            asm volatile("s_waitcnt vmcnt(0)" ::: "memory");
        }
        __builtin_amdgcn_s_barrier();          // raw: does NOT drain vmcnt
        asm volatile("" ::: "memory");         // pin ds_reads below barrier

        const _Float16* As = sm + cur * 16384;
        const _Float16* Bs = As + 8192;
#pragma unroll
        for (int step = 0; step < 2; step++) {
            f16x8 af[4], bf[4];
#pragma unroll
            for (int t = 0; t < 4; t++) {
                int ra = wm * 64 + t * 16 + fr;
                int rb = wn * 64 + t * 16 + fr;
                int kc = ((step * 4 + q) ^ fx) * 8;
                af[t] = *(const f16x8*)&As[ra * 64 + kc];
                bf[t] = *(const f16x8*)&Bs[rb * 64 + kc];
            }
            if (WITH_RS) {
#pragma unroll
                for (int t = 0; t < 4; t++) rs[t] = frag_sum8(af[t], rs[t]);
            }
#pragma unroll
            for (int tm = 0; tm < 4; tm++)
#pragma unroll
                for (int tn = 0; tn < 4; tn++)
                    acc[tm][tn] = __builtin_amdgcn_mfma_f32_16x16x32_f16(
                        af[tm], bf[tn], acc[tm][tn], 0, 0, 0);
        }
        asm volatile("" ::: "memory");         // pin ds_reads above barrier
        if (!more) break;
        __builtin_amdgcn_s_barrier();          // reads done before overwrite
        cur ^= 1;
    }
}

// ---------------- 1. prep: x->fp16 and W->fp16 W^T --------------------------
__global__ __launch_bounds__(256) void prep(
    const float* __restrict__ x,
    const float* __restrict__ Wq, const float* __restrict__ Wk,
    const float* __restrict__ Wv,
    _Float16* __restrict__ Xh,
    _Float16* __restrict__ WqT, _Float16* __restrict__ WkT,
    _Float16* __restrict__ WvT)
{
    const int bid = blockIdx.x;
    if (bid < 8192) {                       // convert x: 8.4M elems / 1024
        int i = (bid * 256 + threadIdx.x) * 4;
        float4 v = *(const float4*)(x + i);
        f16x4 h;
        h.x = (_Float16)v.x; h.y = (_Float16)v.y;
        h.z = (_Float16)v.z; h.w = (_Float16)v.w;
        *(f16x4*)&Xh[i] = h;
    } else {                                // transpose W: 3 x 1024 blocks
        int t = bid - 8192;
        int z = t >> 10;
        const float* W = (z == 0) ? Wq : (z == 1) ? Wk : Wv;
        _Float16* Wt   = (z == 0) ? WqT : (z == 1) ? WkT : WvT;
        int idx = (t & 1023) * 256 + threadIdx.x;
        int n = idx >> 9, k = idx & 511;
        Wt[idx] = (_Float16)W[k * 512 + n];
    }
}

// ---------------- 2. projections --------------------------------------------
// grid (x=128 X-row-tiles, y=4 W-cols, z=3). Same X row-tile across y -> bids
// differ by 128 (=0 mod 8) -> same XCD -> X staged once per XCD L2.
__global__ __launch_bounds__(256) void proj_mfma(
    const _Float16* __restrict__ Xh,
    const _Float16* __restrict__ WqT, const float* __restrict__ bq,
    const _Float16* __restrict__ WkT, const float* __restrict__ bk,
    const _Float16* __restrict__ WvT, const float* __restrict__ bv,
    _Float16* __restrict__ Qh, _Float16* __restrict__ Kh,
    _Float16* __restrict__ Vt)
{
    __shared__ __align__(16) _Float16 smem[4 * 128 * 64];

    const int z = blockIdx.z;
    f32x4 acc[4][4];
#pragma unroll
    for (int i = 0; i < 4; i++)
#pragma unroll
        for (int j = 0; j < 4; j++) acc[i][j] = (f32x4){0.f, 0.f, 0.f, 0.f};
    float rs_unused[4];

    const int lane = threadIdx.x & 63, wave = threadIdx.x >> 6;
    const int wm = wave >> 1, wn = wave & 1;
    const int er = (lane >> 4) * 4, ec = lane & 15;  // C/D: col=lane&15, row=q*4+reg

    if (z < 2) {
        const _Float16* Wt = (z == 0) ? WqT : WkT;
        const float* bias  = (z == 0) ? bq : bk;
        _Float16* P        = (z == 0) ? Qh : Kh;
        const float sc     = (z == 0) ? 0.04419417382415922f : 1.0f;
        const int row0 = blockIdx.x * 128, col0 = blockIdx.y * 128;
        mfma_gemm_core64<false>(Xh, 512, Wt, 512, 512, row0, col0, smem, acc,
                                rs_unused);
#pragma unroll
        for (int tm = 0; tm < 4; tm++)
#pragma unroll
            for (int tn = 0; tn < 4; tn++) {
                int col = col0 + wn * 64 + tn * 16 + ec;
                float bb = bias[col];
#pragma unroll
                for (int r = 0; r < 4; r++) {
                    int row = row0 + wm * 64 + tm * 16 + er + r;
                    P[(size_t)row * 512 + col] = (_Float16)((acc[tm][tn][r] + bb) * sc);
                }
            }
    } else {
        // transposed V: out(row=d, col=s_global) = sum_k WvT[d][k] * Xh[s][k]
        const int row0 = blockIdx.y * 128;   // d (M=512)
        const int col0 = blockIdx.x * 128;   // s_global (N=16384)
        mfma_gemm_core64<false>(WvT, 512, Xh, 512, 512, row0, col0, smem, acc,
                                rs_unused);
#pragma unroll
        for (int tm = 0; tm < 4; tm++)
#pragma unroll
            for (int tn = 0; tn < 4; tn++) {
                int col = col0 + wn * 64 + tn * 16 + ec;   // s_global
                size_t obase = (size_t)(col >> 11) * (512 * 2048) + (col & 2047);
#pragma unroll
                for (int r = 0; r < 4; r++) {
                    int row = row0 + wm * 64 + tm * 16 + er + r;  // d
                    Vt[obase + (size_t)row * 2048] = (_Float16)(acc[tm][tn][r] + bv[row]);
                }
            }
    }
}

// ---------------- 3. scores: P = exp(Q.K^T) (unnormalized) ------------------
// 1-D grid 2048: batch = bid&7 (XCD pin: Q[b]+K[b]=4MB=one XCD L2), col fast.
__global__ __launch_bounds__(256) void scores_mfma(
    const _Float16* __restrict__ Qh, const _Float16* __restrict__ Kh,
    _Float16* __restrict__ Sh)
{
    __shared__ __align__(16) _Float16 smem[4 * 128 * 64];
    const int bid = blockIdx.x;
    const int b   = bid & 7;
    const int rem = bid >> 3;
    const int col0 = (rem & 15) * 128;
    const int row0 = (rem >> 4) * 128;

    const _Float16* A = Qh + (size_t)b * 2048 * 512;
    const _Float16* B = Kh + (size_t)b * 2048 * 512;
    _Float16* S = Sh + (size_t)b * 2048 * 2048;

    f32x4 acc[4][4];
#pragma unroll
    for (int i = 0; i < 4; i++)
#pragma unroll
        for (int j = 0; j < 4; j++) acc[i][j] = (f32x4){0.f, 0.f, 0.f, 0.f};
    float rs_unused[4];

    mfma_gemm_core64<false>(A, 512, B, 512, 512, row0, col0, smem, acc,
                            rs_unused);

    const int lane = threadIdx.x & 63, wave = threadIdx.x >> 6;
    const int wm = wave >> 1, wn = wave & 1;
    const int er = (lane >> 4) * 4, ec = lane & 15;
#pragma unroll
    for (int tm = 0; tm < 4; tm++)
#pragma unroll
        for (int tn = 0; tn < 4; tn++) {
            int col = col0 + wn * 64 + tn * 16 + ec;
#pragma unroll
            for (int r = 0; r < 4; r++) {
                int row = row0 + wm * 64 + tm * 16 + er + r;
                S[(size_t)row * 2048 + col] = (_Float16)__expf(acc[tm][tn][r]);
            }
        }
}

// ---------------- 4. out = (P.V) * mask / rowsum(P) -------------------------
// 1-D grid 512: batch = bid&7 (XCD pin: P[b]=8MB streams through one XCD L2,
// V[b]=2MB resident), col fastest after batch -> the 4 col-blocks of one
// row-group run adjacently and share P rows.
__global__ __launch_bounds__(256) void av_mfma(
    const _Float16* __restrict__ Sh, const _Float16* __restrict__ Vt,
    const float* __restrict__ mask, float* __restrict__ out)
{
    __shared__ __align__(16) _Float16 smem[4 * 128 * 64];
    const int bid = blockIdx.x;
    const int b   = bid & 7;
    const int rem = bid >> 3;
    const int col0 = (rem & 3) * 128;
    const int row0 = (rem >> 2) * 128;

    const _Float16* A = Sh + (size_t)b * 2048 * 2048;
    const _Float16* B = Vt + (size_t)b * 512 * 2048;
    float* O = out + (size_t)b * 2048 * 512;
    const float* mk = mask + (size_t)b * 2048;

    f32x4 acc[4][4];
#pragma unroll
    for (int i = 0; i < 4; i++)
#pragma unroll
        for (int j = 0; j < 4; j++) acc[i][j] = (f32x4){0.f, 0.f, 0.f, 0.f};
    float rs[4] = {0.f, 0.f, 0.f, 0.f};

    mfma_gemm_core64<true>(A, 2048, B, 2048, 2048, row0, col0, smem, acc, rs);

    const int lane = threadIdx.x & 63, wave = threadIdx.x >> 6;
    const int wm = wave >> 1, wn = wave & 1;
    const int er = (lane >> 4) * 4, ec = lane & 15;

    // rs[t]: partial rowsum of row (wm*64+t*16+(lane&15)) over this lane's
    // k-quad; butterfly over 4 quads -> full rowsum.
#pragma unroll
    for (int t = 0; t < 4; t++) {
        rs[t] += __shfl_xor(rs[t], 16, 64);
        rs[t] += __shfl_xor(rs[t], 32, 64);
    }
    // l_s aliases the (now dead) staging LDS to keep static shared at 64KB.
    __syncthreads();                       // all waves out of the GEMM loop
    float* l_s = (float*)smem;
    if (wn == 0 && lane < 16) {
#pragma unroll
        for (int t = 0; t < 4; t++) l_s[wm * 64 + t * 16 + lane] = rs[t];
    }
    __syncthreads();

#pragma unroll
    for (int tm = 0; tm < 4; tm++)
#pragma unroll
        for (int r = 0; r < 4; r++) {
            int lrow = wm * 64 + tm * 16 + er + r;
            int row = row0 + lrow;
            float s = mk[row] / l_s[lrow];
#pragma unroll
            for (int tn = 0; tn < 4; tn++) {
                int col = col0 + wn * 64 + tn * 16 + ec;
                O[(size_t)row * 512 + col] = acc[tm][tn][r] * s;
            }
        }
}

extern "C" void kernel_launch(void* const* d_in, const int* in_sizes, int n_in,
                              void* d_out, int out_size, void* d_ws, size_t ws_size,
                              hipStream_t stream) {
    const float* x    = (const float*)d_in[0];
    const float* mask = (const float*)d_in[1];
    const float* Wq   = (const float*)d_in[2];
    const float* bq   = (const float*)d_in[3];
    const float* Wk   = (const float*)d_in[4];
    const float* bk   = (const float*)d_in[5];
    const float* Wv   = (const float*)d_in[6];
    const float* bv   = (const float*)d_in[7];
    float* out = (float*)d_out;

    const size_t BSD = (size_t)8 * 2048 * 512;       // 8.4M halves
    _Float16* base = (_Float16*)d_ws;
    _Float16* Qh  = base;
    _Float16* Kh  = Qh + BSD;
    _Float16* Vt  = Kh + BSD;                         // [b][d][s]
    _Float16* WqT = Vt + BSD;
    _Float16* WkT = WqT + 512 * 512;
    _Float16* WvT = WkT + 512 * 512;
    _Float16* Xh  = WvT + 512 * 512;
    _Float16* Sh  = Xh;                               // Xh dead after proj

    dim3 blk(256);
    prep<<<dim3(8192 + 3 * 1024), blk, 0, stream>>>(
        x, Wq, Wk, Wv, Xh, WqT, WkT, WvT);
    proj_mfma<<<dim3(128, 4, 3), blk, 0, stream>>>(
        Xh, WqT, bq, WkT, bk, WvT, bv, Qh, Kh, Vt);
    scores_mfma<<<dim3(2048), blk, 0, stream>>>(Qh, Kh, Sh);
    av_mfma<<<dim3(512), blk, 0, stream>>>(Sh, Vt, mask, out);
}

// Round 2
// 217.183 us; speedup vs baseline: 1.0783x; 1.0783x over previous
//
#include <hip/hip_runtime.h>
#include <math.h>
#include <stdint.h>

// B=8, S=2048, D=512 single-head self-attention, fp32 in/out, fp16 MFMA inside.
// Round 9: all GEMMs moved to a phase-split 256x128 pipelined core (T2+T3+T4+T5):
//   - 8 waves (512 thr), per-wave 64x64 (MF=4,NF=4), BK=64, dbuf LDS 96KB.
//   - 4 phases per K-tile: {A0.B0}{A0.B1}{A1.B1}{A1.B0}; B0 register-held
//     across the tile so phase 3 needs no LDS reads.
//   - tile t+2 staged once per tile right after the mid-tile barrier (buffer
//     just freed); s_waitcnt vmcnt(6) keeps 6 loads in flight across BOTH
//     barriers; vmcnt never drains to 0 in the main loop.
//   - setprio(1) around each 8-MFMA cluster; unroll-2 K-loop makes buffer
//     parity + all ds_read addresses loop-invariant (r1 post-mortem: av was
//     VALU-addressing-bound, VALUBusy 44% > MfmaUtil 23%).
// Round-8 lesson: counted-vmcnt grafted on the lockstep 2-phase loop = null
// (matches learn_hip m230/m248 regime gate); per-SIMD MFMA cost is 19.4cyc
// (not 4.85 - that is per-CU), so av's MFMA floor is ~16.6us of 57.9us wall.
// Round-7: XCD-aware block mapping (batch=bid&7) kept everywhere.
//
//  1. prep:        Xh = fp16(x);  W*T = fp16(W^T) for q,k,v
//  2. proj_mfma:   z=0: Qh = (Xh.Wq + bq)/sqrt(512)   z=1: Kh = Xh.Wk + bk
//                  z=2: Vt[b][d][s] = (Xh.Wv + bv)^T  (direct transposed GEMM)
//  3. scores_mfma: P[b] = fp16(exp(Qh.Kh^T))  UNNORMALIZED (scores ~N(0,1))
//  4. av_mfma:     out[b] = (P.V) * mask[row] / l[row]; l = rowsum(P) via
//                  fdot2 on fresh A-frags (phases 0 and 2 only).

typedef _Float16 f16x8 __attribute__((ext_vector_type(8)));
typedef _Float16 f16x4 __attribute__((ext_vector_type(4)));
typedef _Float16 f16x2 __attribute__((ext_vector_type(2)));
typedef float f32x4 __attribute__((ext_vector_type(4)));

__device__ __forceinline__ void async16(const _Float16* g, _Float16* l) {
    __builtin_amdgcn_global_load_lds(
        (const __attribute__((address_space(1))) unsigned int*)(uintptr_t)g,
        (__attribute__((address_space(3))) unsigned int*)(unsigned int)(uintptr_t)l,
        16, 0, 0);
}

__device__ __forceinline__ float frag_sum8(f16x8 v, float acc) {
#if __has_builtin(__builtin_amdgcn_fdot2)
    const f16x2 one2 = {(_Float16)1.f, (_Float16)1.f};
    const f16x2* p = (const f16x2*)&v;
    acc = __builtin_amdgcn_fdot2(p[0], one2, acc, false);
    acc = __builtin_amdgcn_fdot2(p[1], one2, acc, false);
    acc = __builtin_amdgcn_fdot2(p[2], one2, acc, false);
    acc = __builtin_amdgcn_fdot2(p[3], one2, acc, false);
#else
#pragma unroll
    for (int j = 0; j < 8; j++) acc += (float)v[j];
#endif
    return acc;
}

// ---------------------------------------------------------------------------
// Pipelined 256x128 GEMM core: acc[4][4] += A[row0:+256][0:K].B[col0:+128][0:K]^T
// A:[M][K], B:[N][K], lda==ldb==ld. 8 waves as 4(wm) x 2(wn), per-wave 64x64.
// LDS chunks: 8 rows x 64 halves = 1KB each; A = chunks 0..31, B = 32..47.
// Chunk c staged by one async16: lane l writes bytes l*16, i.e. row 8c+(l>>3),
// cols ((l&7)^(l>>3))*8  (pre-swizzled global source, linear LDS dest).
// Read back: A[row][k0*8..] lives at As[row*64 + ((k0)^(row&7))*8].
// ---------------------------------------------------------------------------
template <bool WITH_RS>
__device__ __forceinline__ void core8(
    const _Float16* __restrict__ A,
    const _Float16* __restrict__ B,
    int ld, int K, int row0, int col0,
    _Float16* sm, f32x4 acc[4][4], float rs[4])
{
    constexpr int CA = 32, L = 6, BUFH = 24576;  // halves per buffer (48KB)
    const int tid = threadIdx.x, lane = tid & 63, wave = tid >> 6;
    const int wm = wave >> 1, wn = wave & 1;
    const int rc  = lane >> 3;
    const int swz = ((lane & 7) ^ rc) * 8;
    const int fr = lane & 15, q = lane >> 4, fx = fr & 7;

    const _Float16* g[L];
    int coff[L];
#pragma unroll
    for (int i = 0; i < L; i++) {
        int c = wave * L + i;
        const _Float16* base = (c < CA) ? A : B;
        int rr = (c < CA) ? (row0 + 8 * c) : (col0 + 8 * (c - CA));
        g[i]    = base + (size_t)(rr + rc) * ld + swz;
        coff[i] = c * 512;
    }

    const int NT = K >> 6;
    // prologue: stage tiles 0 (buf0) and 1 (buf1); leave tile1's 6 in flight
#pragma unroll
    for (int i = 0; i < L; i++) async16(g[i], sm + coff[i]);
#pragma unroll
    for (int i = 0; i < L; i++) async16(g[i] + 64, sm + BUFH + coff[i]);
#pragma unroll
    for (int i = 0; i < L; i++) g[i] += 128;     // -> tile 2
    asm volatile("s_waitcnt vmcnt(6)" ::: "memory");
    asm volatile("" ::: "memory");
    __builtin_amdgcn_s_barrier();
    asm volatile("" ::: "memory");

#pragma unroll 2
    for (int t = 0; t < NT; ++t) {
        const _Float16* As = sm + (t & 1) * BUFH;
        const _Float16* Bs = As + CA * 512;
        f16x8 ah[2][2], b0[2][2], b1[2][2];

        // ---- phase 0: read A-half0 + B-half0, MFMA quadrant (0,0)
#pragma unroll
        for (int m = 0; m < 2; m++)
#pragma unroll
            for (int s = 0; s < 2; s++) {
                int ra = (wm * 4 + m) * 16 + fr;
                int kc = ((s * 4 + q) ^ fx) * 8;
                ah[m][s] = *(const f16x8*)&As[ra * 64 + kc];
            }
#pragma unroll
        for (int n = 0; n < 2; n++)
#pragma unroll
            for (int s = 0; s < 2; s++) {
                int rb = (wn * 4 + n) * 16 + fr;
                int kc = ((s * 4 + q) ^ fx) * 8;
                b0[n][s] = *(const f16x8*)&Bs[rb * 64 + kc];
            }
        if (WITH_RS) {
#pragma unroll
            for (int m = 0; m < 2; m++)
#pragma unroll
                for (int s = 0; s < 2; s++) rs[m] = frag_sum8(ah[m][s], rs[m]);
        }
        __builtin_amdgcn_s_setprio(1);
#pragma unroll
        for (int m = 0; m < 2; m++)
#pragma unroll
            for (int n = 0; n < 2; n++)
#pragma unroll
                for (int s = 0; s < 2; s++)
                    acc[m][n] = __builtin_amdgcn_mfma_f32_16x16x32_f16(
                        ah[m][s], b0[n][s], acc[m][n], 0, 0, 0);
        __builtin_amdgcn_s_setprio(0);

        // ---- phase 1: read B-half1, MFMA quadrant (0,1)
#pragma unroll
        for (int n = 0; n < 2; n++)
#pragma unroll
            for (int s = 0; s < 2; s++) {
                int rb = (wn * 4 + 2 + n) * 16 + fr;
                int kc = ((s * 4 + q) ^ fx) * 8;
                b1[n][s] = *(const f16x8*)&Bs[rb * 64 + kc];
            }
        __builtin_amdgcn_s_setprio(1);
#pragma unroll
        for (int m = 0; m < 2; m++)
#pragma unroll
            for (int n = 0; n < 2; n++)
#pragma unroll
                for (int s = 0; s < 2; s++)
                    acc[m][2 + n] = __builtin_amdgcn_mfma_f32_16x16x32_f16(
                        ah[m][s], b1[n][s], acc[m][2 + n], 0, 0, 0);
        __builtin_amdgcn_s_setprio(0);

        // ---- phase 2: read A-half1, MFMA quadrant (1,1)
#pragma unroll
        for (int m = 0; m < 2; m++)
#pragma unroll
            for (int s = 0; s < 2; s++) {
                int ra = (wm * 4 + 2 + m) * 16 + fr;
                int kc = ((s * 4 + q) ^ fx) * 8;
                ah[m][s] = *(const f16x8*)&As[ra * 64 + kc];
            }
        if (WITH_RS) {
#pragma unroll
            for (int m = 0; m < 2; m++)
#pragma unroll
                for (int s = 0; s < 2; s++) rs[2 + m] = frag_sum8(ah[m][s], rs[2 + m]);
        }
        __builtin_amdgcn_s_setprio(1);
#pragma unroll
        for (int m = 0; m < 2; m++)
#pragma unroll
            for (int n = 0; n < 2; n++)
#pragma unroll
                for (int s = 0; s < 2; s++)
                    acc[2 + m][2 + n] = __builtin_amdgcn_mfma_f32_16x16x32_f16(
                        ah[m][s], b1[n][s], acc[2 + m][2 + n], 0, 0, 0);
        __builtin_amdgcn_s_setprio(0);

        // ---- phase 3: barrier (reads of buf[t&1] all done: lgkmcnt(0)),
        //      stage tile t+2 into the freed buffer, MFMA quadrant (1,0)
        //      on register-held A1/B0, counted vmcnt, barrier.
        asm volatile("s_waitcnt lgkmcnt(0)" ::: "memory");
        asm volatile("" ::: "memory");
        __builtin_amdgcn_s_barrier();
        asm volatile("" ::: "memory");
        if (t + 2 < NT) {
            _Float16* db = sm + (t & 1) * BUFH;
#pragma unroll
            for (int i = 0; i < L; i++) async16(g[i], db + coff[i]);
#pragma unroll
            for (int i = 0; i < L; i++) g[i] += 64;
        }
        __builtin_amdgcn_s_setprio(1);
#pragma unroll
        for (int m = 0; m < 2; m++)
#pragma unroll
            for (int n = 0; n < 2; n++)
#pragma unroll
                for (int s = 0; s < 2; s++)
                    acc[2 + m][n] = __builtin_amdgcn_mfma_f32_16x16x32_f16(
                        ah[m][s], b0[n][s], acc[2 + m][n], 0, 0, 0);
        __builtin_amdgcn_s_setprio(0);
        if (t + 2 < NT) {
            asm volatile("s_waitcnt vmcnt(6)" ::: "memory");
        } else if (t + 1 < NT) {
            asm volatile("s_waitcnt vmcnt(0)" ::: "memory");
        }
        if (t + 1 < NT) {
            asm volatile("" ::: "memory");
            __builtin_amdgcn_s_barrier();
            asm volatile("" ::: "memory");
        }
    }
}

// ---------------- 1. prep: x->fp16 and W->fp16 W^T --------------------------
__global__ __launch_bounds__(256) void prep(
    const float* __restrict__ x,
    const float* __restrict__ Wq, const float* __restrict__ Wk,
    const float* __restrict__ Wv,
    _Float16* __restrict__ Xh,
    _Float16* __restrict__ WqT, _Float16* __restrict__ WkT,
    _Float16* __restrict__ WvT)
{
    const int bid = blockIdx.x;
    if (bid < 8192) {                       // convert x: 8.4M elems / 1024
        int i = (bid * 256 + threadIdx.x) * 4;
        float4 v = *(const float4*)(x + i);
        f16x4 h;
        h.x = (_Float16)v.x; h.y = (_Float16)v.y;
        h.z = (_Float16)v.z; h.w = (_Float16)v.w;
        *(f16x4*)&Xh[i] = h;
    } else {                                // transpose W: 3 x 1024 blocks
        int t = bid - 8192;
        int z = t >> 10;
        const float* W = (z == 0) ? Wq : (z == 1) ? Wk : Wv;
        _Float16* Wt   = (z == 0) ? WqT : (z == 1) ? WkT : WvT;
        int idx = (t & 1023) * 256 + threadIdx.x;
        int n = idx >> 9, k = idx & 511;
        Wt[idx] = (_Float16)W[k * 512 + n];
    }
}

// ---------------- 2. projections --------------------------------------------
// grid (x=64, y=4, z=3), 512 thr. z<2: row0=bx*256 (X rows), col0=by*128.
// z=2: idx=by*64+bx in [0,256): row0=(idx>>7)*256 (d), col0=(idx&127)*128 (s).
__global__ __launch_bounds__(512, 2) void proj_mfma(
    const _Float16* __restrict__ Xh,
    const _Float16* __restrict__ WqT, const float* __restrict__ bq,
    const _Float16* __restrict__ WkT, const float* __restrict__ bk,
    const _Float16* __restrict__ WvT, const float* __restrict__ bv,
    _Float16* __restrict__ Qh, _Float16* __restrict__ Kh,
    _Float16* __restrict__ Vt)
{
    __shared__ __align__(16) _Float16 smem[2 * 24576];

    const int z = blockIdx.z;
    f32x4 acc[4][4];
#pragma unroll
    for (int i = 0; i < 4; i++)
#pragma unroll
        for (int j = 0; j < 4; j++) acc[i][j] = (f32x4){0.f, 0.f, 0.f, 0.f};
    float rs_unused[4];

    const int lane = threadIdx.x & 63, wave = threadIdx.x >> 6;
    const int wm = wave >> 1, wn = wave & 1;
    const int er = (lane >> 4) * 4, ec = lane & 15;  // C/D: col=lane&15, row=q*4+reg

    if (z < 2) {
        const _Float16* Wt = (z == 0) ? WqT : WkT;
        const float* bias  = (z == 0) ? bq : bk;
        _Float16* P        = (z == 0) ? Qh : Kh;
        const float sc     = (z == 0) ? 0.04419417382415922f : 1.0f;
        const int row0 = blockIdx.x * 256, col0 = blockIdx.y * 128;
        core8<false>(Xh, Wt, 512, 512, row0, col0, smem, acc, rs_unused);
#pragma unroll
        for (int mf = 0; mf < 4; mf++)
#pragma unroll
            for (int nf = 0; nf < 4; nf++) {
                int col = col0 + (wn * 4 + nf) * 16 + ec;
                float bb = bias[col];
#pragma unroll
                for (int r = 0; r < 4; r++) {
                    int row = row0 + (wm * 4 + mf) * 16 + er + r;
                    P[(size_t)row * 512 + col] = (_Float16)((acc[mf][nf][r] + bb) * sc);
                }
            }
    } else {
        // transposed V: out(row=d, col=s_global) = sum_k WvT[d][k] * Xh[s][k]
        const int idx = blockIdx.y * 64 + blockIdx.x;
        const int row0 = (idx >> 7) * 256;   // d (M=512)
        const int col0 = (idx & 127) * 128;  // s_global (N=16384)
        core8<false>(WvT, Xh, 512, 512, row0, col0, smem, acc, rs_unused);
#pragma unroll
        for (int mf = 0; mf < 4; mf++)
#pragma unroll
            for (int nf = 0; nf < 4; nf++) {
                int col = col0 + (wn * 4 + nf) * 16 + ec;   // s_global
                size_t obase = (size_t)(col >> 11) * (512 * 2048) + (col & 2047);
#pragma unroll
                for (int r = 0; r < 4; r++) {
                    int row = row0 + (wm * 4 + mf) * 16 + er + r;  // d
                    Vt[obase + (size_t)row * 2048] = (_Float16)(acc[mf][nf][r] + bv[row]);
                }
            }
    }
}

// ---------------- 3. scores: P = exp(Q.K^T) (unnormalized) ------------------
// 1-D grid 1024: batch = bid&7 (XCD pin), rem=bid>>3: col0=(rem&15)*128,
// row0=(rem>>4)*256.
__global__ __launch_bounds__(512, 2) void scores_mfma(
    const _Float16* __restrict__ Qh, const _Float16* __restrict__ Kh,
    _Float16* __restrict__ Sh)
{
    __shared__ __align__(16) _Float16 smem[2 * 24576];
    const int bid = blockIdx.x;
    const int b   = bid & 7;
    const int rem = bid >> 3;
    const int col0 = (rem & 15) * 128;
    const int row0 = (rem >> 4) * 256;

    const _Float16* A = Qh + (size_t)b * 2048 * 512;
    const _Float16* B = Kh + (size_t)b * 2048 * 512;
    _Float16* S = Sh + (size_t)b * 2048 * 2048;

    f32x4 acc[4][4];
#pragma unroll
    for (int i = 0; i < 4; i++)
#pragma unroll
        for (int j = 0; j < 4; j++) acc[i][j] = (f32x4){0.f, 0.f, 0.f, 0.f};
    float rs_unused[4];

    core8<false>(A, B, 512, 512, row0, col0, smem, acc, rs_unused);

    const int lane = threadIdx.x & 63, wave = threadIdx.x >> 6;
    const int wm = wave >> 1, wn = wave & 1;
    const int er = (lane >> 4) * 4, ec = lane & 15;
#pragma unroll
    for (int mf = 0; mf < 4; mf++)
#pragma unroll
        for (int nf = 0; nf < 4; nf++) {
            int col = col0 + (wn * 4 + nf) * 16 + ec;
#pragma unroll
            for (int r = 0; r < 4; r++) {
                int row = row0 + (wm * 4 + mf) * 16 + er + r;
                S[(size_t)row * 2048 + col] = (_Float16)__expf(acc[mf][nf][r]);
            }
        }
}

// ---------------- 4. out = (P.V) * mask / rowsum(P) -------------------------
// 1-D grid 256: batch = bid&7, rem=bid>>3 in [0,32): col0=(rem&3)*128,
// row0=(rem>>2)*256.
__global__ __launch_bounds__(512, 2) void av_mfma(
    const _Float16* __restrict__ Sh, const _Float16* __restrict__ Vt,
    const float* __restrict__ mask, float* __restrict__ out)
{
    __shared__ __align__(16) _Float16 smem[2 * 24576];
    const int bid = blockIdx.x;
    const int b   = bid & 7;
    const int rem = bid >> 3;
    const int col0 = (rem & 3) * 128;
    const int row0 = (rem >> 2) * 256;

    const _Float16* A = Sh + (size_t)b * 2048 * 2048;
    const _Float16* B = Vt + (size_t)b * 512 * 2048;
    float* O = out + (size_t)b * 2048 * 512;
    const float* mk = mask + (size_t)b * 2048;

    f32x4 acc[4][4];
#pragma unroll
    for (int i = 0; i < 4; i++)
#pragma unroll
        for (int j = 0; j < 4; j++) acc[i][j] = (f32x4){0.f, 0.f, 0.f, 0.f};
    float rs[4] = {0.f, 0.f, 0.f, 0.f};

    core8<true>(A, B, 2048, 2048, row0, col0, smem, acc, rs);

    const int lane = threadIdx.x & 63, wave = threadIdx.x >> 6;
    const int wm = wave >> 1, wn = wave & 1;
    const int er = (lane >> 4) * 4, ec = lane & 15;

    // rs[mf]: partial rowsum of row (wm*64 + mf*16 + (lane&15)) over this
    // lane's k-chunks; butterfly over the 4 q-groups -> full rowsum.
#pragma unroll
    for (int mf = 0; mf < 4; mf++) {
        rs[mf] += __shfl_xor(rs[mf], 16, 64);
        rs[mf] += __shfl_xor(rs[mf], 32, 64);
    }
    __syncthreads();                       // all waves out of the GEMM loop
    float* l_s = (float*)smem;             // alias dead staging LDS
    if (wn == 0 && lane < 16) {
#pragma unroll
        for (int mf = 0; mf < 4; mf++) l_s[wm * 64 + mf * 16 + lane] = rs[mf];
    }
    __syncthreads();

#pragma unroll
    for (int mf = 0; mf < 4; mf++)
#pragma unroll
        for (int r = 0; r < 4; r++) {
            int lrow = wm * 64 + mf * 16 + er + r;
            int row = row0 + lrow;
            float s = mk[row] / l_s[lrow];
#pragma unroll
            for (int nf = 0; nf < 4; nf++) {
                int col = col0 + (wn * 4 + nf) * 16 + ec;
                O[(size_t)row * 512 + col] = acc[mf][nf][r] * s;
            }
        }
}

extern "C" void kernel_launch(void* const* d_in, const int* in_sizes, int n_in,
                              void* d_out, int out_size, void* d_ws, size_t ws_size,
                              hipStream_t stream) {
    const float* x    = (const float*)d_in[0];
    const float* mask = (const float*)d_in[1];
    const float* Wq   = (const float*)d_in[2];
    const float* bq   = (const float*)d_in[3];
    const float* Wk   = (const float*)d_in[4];
    const float* bk   = (const float*)d_in[5];
    const float* Wv   = (const float*)d_in[6];
    const float* bv   = (const float*)d_in[7];
    float* out = (float*)d_out;

    const size_t BSD = (size_t)8 * 2048 * 512;       // 8.4M halves
    _Float16* base = (_Float16*)d_ws;
    _Float16* Qh  = base;
    _Float16* Kh  = Qh + BSD;
    _Float16* Vt  = Kh + BSD;                         // [b][d][s]
    _Float16* WqT = Vt + BSD;
    _Float16* WkT = WqT + 512 * 512;
    _Float16* WvT = WkT + 512 * 512;
    _Float16* Xh  = WvT + 512 * 512;
    _Float16* Sh  = Xh;                               // Xh dead after proj

    prep<<<dim3(8192 + 3 * 1024), dim3(256), 0, stream>>>(
        x, Wq, Wk, Wv, Xh, WqT, WkT, WvT);
    proj_mfma<<<dim3(64, 4, 3), dim3(512), 0, stream>>>(
        Xh, WqT, bq, WkT, bk, WvT, bv, Qh, Kh, Vt);
    scores_mfma<<<dim3(1024), dim3(512), 0, stream>>>(Qh, Kh, Sh);
    av_mfma<<<dim3(256), dim3(512), 0, stream>>>(Sh, Vt, mask, out);
}